// Round 3
// baseline (172.270 us; speedup 1.0000x reference)
//
#include <hip/hip_runtime.h>
#include <math.h>

// RESUS_NN_2327872274812: Q=8192, S=30, D=512.
// Kernel 1: lane = query. All 64 lanes of a wave process the same (s, d)
// => support[s][d] and fc1_w[d] are wave-uniform => scalar (SGPR) loads.
// Inner loop is pure VALU: v_subrev(sgpr) / v_fma(sgpr, abs) / v_fmac.
// D split: 4 k-sets (blockIdx.y) x 8 waves x 16 d. Wave partials combined
// in LDS (ds_add), block writes deterministic partials to d_ws.
// Kernel 2: per-query softmax / dy-dot / sqrt-mean epilogue.

#define QN 8192
#define SN 30
#define DN 512
#define KSETS 4          // blockIdx.y
#define WPB 8            // waves per block
#define BLK (WPB * 64)   // 512 threads
#define DW 16            // d elements per wave slice (KSETS*WPB*DW = 512)
#define QG 64            // queries per block (one per lane)

__global__ __launch_bounds__(BLK, 2)
void k_partial(const float* __restrict__ query,    // [Q][D]
               const float* __restrict__ support,  // [S][D]
               const float* __restrict__ fc1_w,    // [D]
               float* __restrict__ part)           // [KSETS][60][QN]
{
    // acc[a][lane]: a = 0..29 score partial, a = 30..59 sq partial
    __shared__ float acc[60 * QG];   // 15360 B

    const int tid = threadIdx.x;
    for (int i = tid; i < 60 * QG; i += BLK) acc[i] = 0.0f;

    const int lane = tid & 63;
    const int wv   = __builtin_amdgcn_readfirstlane(tid >> 6);  // 0..7, uniform
    const int kset = blockIdx.y;                                 // 0..3
    const int kb   = kset * (WPB * DW) + wv * DW;                // uniform
    const int qg   = blockIdx.x;                                 // 0..127
    const int q    = qg * QG + lane;

    // this lane's 16 query values (one 64B cache line per lane)
    float qv[DW];
    {
        const float* qrow = query + (size_t)q * DN + kb;
#pragma unroll
        for (int j = 0; j < DW / 4; ++j) {
            float4 t = *reinterpret_cast<const float4*>(qrow + 4 * j);
            qv[4 * j + 0] = t.x; qv[4 * j + 1] = t.y;
            qv[4 * j + 2] = t.z; qv[4 * j + 3] = t.w;
        }
    }
    // wave-uniform weight slice -> SGPRs
    float wreg[DW];
#pragma unroll
    for (int j = 0; j < DW; ++j) wreg[j] = fc1_w[kb + j];

    __syncthreads();   // LDS zeroed

#pragma unroll 2
    for (int s = 0; s < SN; ++s) {
        const float* srow = support + (size_t)s * DN + kb;  // uniform addr
        float sc = 0.0f, sq = 0.0f;
#pragma unroll
        for (int j = 0; j < DW; ++j) {
            float d = qv[j] - srow[j];          // subrev with sgpr src0
            sc = fmaf(wreg[j], fabsf(d), sc);   // fma: sgpr, abs(vgpr), vgpr
            sq = fmaf(d, d, sq);
        }
        atomicAdd(&acc[s * QG + lane], sc);
        atomicAdd(&acc[(SN + s) * QG + lane], sq);
    }
    __syncthreads();

    // flush block partials: part[kset][a][qg*64 + l], coalesced
    float* dst = part + (size_t)kset * 60 * QN + (size_t)qg * QG;
    for (int i = tid; i < 60 * QG; i += BLK) {
        int a = i >> 6, l = i & 63;
        dst[(size_t)a * QN + l] = acc[i];
    }
}

__global__ __launch_bounds__(256, 1)
void k_final(const float* __restrict__ part,      // [KSETS][60][QN]
             const float* __restrict__ support_y, // [S]
             const float* __restrict__ support_pr,// [S]
             const float* __restrict__ query_pr,  // [Q]
             const float* __restrict__ adj_scale, // [30]
             const float* __restrict__ adj_bias,  // [30]
             const int*   __restrict__ num_samples,
             float* __restrict__ out)             // [2*Q]
{
    const int q = blockIdx.x * 256 + threadIdx.x;

    float m = -1e30f, den = 0.0f, num = 0.0f, l2 = 0.0f;
#pragma unroll 2
    for (int s = 0; s < SN; ++s) {
        float sc = 0.0f, ss = 0.0f;
#pragma unroll
        for (int k = 0; k < KSETS; ++k) {
            sc += part[((size_t)k * 60 + s) * QN + q];
            ss += part[((size_t)k * 60 + SN + s) * QN + q];
        }
        const float dy = support_y[s] - 1.0f / (1.0f + expf(-support_pr[s]));
        // online softmax
        const float mn = fmaxf(m, sc);
        const float sm = expf(m - mn);
        const float e  = expf(sc - mn);
        den = den * sm + e;
        num = fmaf(dy, e, num * sm);
        m = mn;
        l2 += sqrtf(ss);
    }

    const int ns = num_samples[0];
    const float scale = fabsf(adj_scale[ns - 1]);
    const float bias  = adj_bias[ns - 1];
    out[q]      = num / den * scale + bias + query_pr[q];
    out[QN + q] = l2 * (1.0f / (float)SN);
}

extern "C" void kernel_launch(void* const* d_in, const int* in_sizes, int n_in,
                              void* d_out, int out_size, void* d_ws, size_t ws_size,
                              hipStream_t stream)
{
    const float* query      = (const float*)d_in[0];
    const float* support    = (const float*)d_in[1];
    const float* support_y  = (const float*)d_in[2];
    const float* support_pr = (const float*)d_in[3];
    const float* query_pr   = (const float*)d_in[4];
    const float* fc1_w      = (const float*)d_in[5];
    // d_in[6] = fc1_b: cancels in softmax, unused
    const float* adj_scale  = (const float*)d_in[7];
    const float* adj_bias   = (const float*)d_in[8];
    const int*   num_s      = (const int*)d_in[9];
    float* out  = (float*)d_out;
    float* part = (float*)d_ws;   // KSETS*60*QN*4 = 7,864,320 B

    dim3 g1(QN / QG, KSETS);      // 128 x 4 = 512 blocks
    hipLaunchKernelGGL(k_partial, g1, dim3(BLK), 0, stream,
                       query, support, fc1_w, part);

    dim3 g2(QN / 256);            // 32 blocks
    hipLaunchKernelGGL(k_final, g2, dim3(256), 0, stream,
                       part, support_y, support_pr, query_pr,
                       adj_scale, adj_bias, num_s, out);
}

// Round 4
// 166.219 us; speedup vs baseline: 1.0364x; 1.0364x over previous
//
#include <hip/hip_runtime.h>
#include <math.h>

// RESUS_NN_2327872274812: Q=8192, S=30, D=512.
// k_partial: lane = query (64 q/wave), wave owns a 16-d slice. ALL per-thread
// state lives in NAMED float4 locals (no indexed arrays -> no scratch
// demotion, the failure mode of rounds 1-3). Support slice is software-
// prefetched one s-iteration ahead so each iteration's load wait is already
// complete. Per-query partials combined across the 32 d-slices via LDS
// ds_add + deterministic global partials in d_ws.
// k_final: lane = s (32-lane group per query), shuffle-reduce softmax.

#define QN 8192
#define SN 30
#define DN 512
#define KSETS 4          // blockIdx.y
#define WPB 8            // waves per block
#define BLK (WPB * 64)   // 512 threads
#define DW 16            // d elements per wave slice (KSETS*WPB*DW = 512)
#define QG 64            // queries per block (one per lane)

__global__ __launch_bounds__(BLK, 2)
void k_partial(const float* __restrict__ query,    // [Q][D]
               const float* __restrict__ support,  // [S][D]
               const float* __restrict__ fc1_w,    // [D]
               float* __restrict__ part)           // [KSETS][60][QN]
{
    __shared__ float acc[60 * QG];   // 15360 B: a<30 score, a>=30 sq

    const int tid = threadIdx.x;
    for (int i = tid; i < 60 * QG; i += BLK) acc[i] = 0.0f;

    const int lane = tid & 63;
    const int wv   = tid >> 6;            // 0..7
    const int kset = blockIdx.y;          // 0..3
    const int kb   = kset * (WPB * DW) + wv * DW;
    const int qg   = blockIdx.x;          // 0..127
    const int q    = qg * QG + lane;

    // query + weight slices: NAMED float4 locals only
    const float4* qrow = reinterpret_cast<const float4*>(query + (size_t)q * DN + kb);
    const float4  q0 = qrow[0], q1 = qrow[1], q2 = qrow[2], q3 = qrow[3];
    const float4* wrow = reinterpret_cast<const float4*>(fc1_w + kb);
    const float4  w0 = wrow[0], w1 = wrow[1], w2 = wrow[2], w3 = wrow[3];

    __syncthreads();   // acc zeroed

    // software prefetch: support slice for s = 0
    const float4* sr = reinterpret_cast<const float4*>(support + kb);
    float4 n0 = sr[0], n1 = sr[1], n2 = sr[2], n3 = sr[3];

    for (int s = 0; s < SN; ++s) {
        const float4 c0 = n0, c1 = n1, c2 = n2, c3 = n3;
        if (s + 1 < SN) {
            const float4* nx = reinterpret_cast<const float4*>(
                support + (size_t)(s + 1) * DN + kb);
            n0 = nx[0]; n1 = nx[1]; n2 = nx[2]; n3 = nx[3];
        }

        float sc = 0.0f, sq = 0.0f;
#define ACC1(QQ, SS, WW) { const float d_ = (QQ) - (SS); \
        sc = fmaf((WW), fabsf(d_), sc); sq = fmaf(d_, d_, sq); }
        ACC1(q0.x, c0.x, w0.x) ACC1(q0.y, c0.y, w0.y)
        ACC1(q0.z, c0.z, w0.z) ACC1(q0.w, c0.w, w0.w)
        ACC1(q1.x, c1.x, w1.x) ACC1(q1.y, c1.y, w1.y)
        ACC1(q1.z, c1.z, w1.z) ACC1(q1.w, c1.w, w1.w)
        ACC1(q2.x, c2.x, w2.x) ACC1(q2.y, c2.y, w2.y)
        ACC1(q2.z, c2.z, w2.z) ACC1(q2.w, c2.w, w2.w)
        ACC1(q3.x, c3.x, w3.x) ACC1(q3.y, c3.y, w3.y)
        ACC1(q3.z, c3.z, w3.z) ACC1(q3.w, c3.w, w3.w)
#undef ACC1

        atomicAdd(&acc[s * QG + lane], sc);            // 2-way bank alias: free
        atomicAdd(&acc[(SN + s) * QG + lane], sq);
    }
    __syncthreads();

    // flush deterministic block partials: part[kset][a][qg*64 + l]
    float* dst = part + (size_t)kset * 60 * QN + (size_t)qg * QG;
    for (int i = tid; i < 60 * QG; i += BLK)
        dst[(size_t)(i >> 6) * QN + (i & 63)] = acc[i];
}

__global__ __launch_bounds__(256, 2)
void k_final(const float* __restrict__ part,      // [KSETS][60][QN]
             const float* __restrict__ support_y, // [S]
             const float* __restrict__ support_pr,// [S]
             const float* __restrict__ query_pr,  // [Q]
             const float* __restrict__ adj_scale, // [30]
             const float* __restrict__ adj_bias,  // [30]
             const int*   __restrict__ num_samples,
             float* __restrict__ out)             // [2*Q]
{
    const int tid  = threadIdx.x;
    const int lane = tid & 63;
    const int widx = tid >> 6;          // wave in block: 0..3
    const int half = lane >> 5;         // 0/1: which query of the wave
    const int s    = lane & 31;         // support index, valid if < 30
    const int q    = blockIdx.x * 8 + widx * 2 + half;

    const bool valid = (s < SN);
    const int  si    = valid ? s : 0;

    float scv = 0.0f, ssv = 0.0f;
#pragma unroll
    for (int k = 0; k < KSETS; ++k) {   // 8 independent batched loads
        scv += part[((size_t)k * 60 + si) * QN + q];
        ssv += part[((size_t)k * 60 + SN + si) * QN + q];
    }
    const float dy = support_y[si] - 1.0f / (1.0f + expf(-support_pr[si]));
    if (!valid) { scv = -1e30f; ssv = 0.0f; }

    // max over the 32-lane group (xor<32 never crosses the half boundary)
    float m = scv;
#pragma unroll
    for (int off = 16; off >= 1; off >>= 1)
        m = fmaxf(m, __shfl_xor(m, off));

    float e   = valid ? expf(scv - m) : 0.0f;
    float den = e;
    float num = dy * e;
    float l2  = valid ? sqrtf(ssv) : 0.0f;
#pragma unroll
    for (int off = 16; off >= 1; off >>= 1) {
        den += __shfl_xor(den, off);
        num += __shfl_xor(num, off);
        l2  += __shfl_xor(l2,  off);
    }

    if (s == 0) {
        const int   ns    = num_samples[0];
        const float scale = fabsf(adj_scale[ns - 1]);
        const float bias  = adj_bias[ns - 1];
        out[q]      = num / den * scale + bias + query_pr[q];
        out[QN + q] = l2 * (1.0f / (float)SN);
    }
}

extern "C" void kernel_launch(void* const* d_in, const int* in_sizes, int n_in,
                              void* d_out, int out_size, void* d_ws, size_t ws_size,
                              hipStream_t stream)
{
    const float* query      = (const float*)d_in[0];
    const float* support    = (const float*)d_in[1];
    const float* support_y  = (const float*)d_in[2];
    const float* support_pr = (const float*)d_in[3];
    const float* query_pr   = (const float*)d_in[4];
    const float* fc1_w      = (const float*)d_in[5];
    // d_in[6] = fc1_b: cancels in softmax, unused
    const float* adj_scale  = (const float*)d_in[7];
    const float* adj_bias   = (const float*)d_in[8];
    const int*   num_s      = (const int*)d_in[9];
    float* out  = (float*)d_out;
    float* part = (float*)d_ws;   // KSETS*60*QN*4 = 7,864,320 B

    dim3 g1(QN / QG, KSETS);      // 128 x 4 = 512 blocks
    hipLaunchKernelGGL(k_partial, g1, dim3(BLK), 0, stream,
                       query, support, fc1_w, part);

    dim3 g2(QN / 8);              // 1024 blocks, 8 queries each
    hipLaunchKernelGGL(k_final, g2, dim3(256), 0, stream,
                       part, support_y, support_pr, query_pr,
                       adj_scale, adj_bias, num_s, out);
}

// Round 5
// 105.235 us; speedup vs baseline: 1.6370x; 1.5795x over previous
//
#include <hip/hip_runtime.h>
#include <math.h>

// RESUS_NN_2327872274812: Q=8192, S=30, D=512.
// Single kernel. lane = (h, s): h = d-half (0/1), s = support row (0..29).
// - support: staged once to LDS, padded row stride 516 floats (2064 B,
//   16B-aligned; 516 % 32 = 4 -> per-instr lanes spread 8 bank-quads evenly).
//   Per-lane-row ds_read_b128 (the only per-lane-scattered access, now on LDS).
// - query / fc1_w: read from global with only 2 DISTINCT addresses per wave
//   (h-dependent) -> 2 transactions per instr, L1-hot. This kills the
//   2KB-lane-stride uncoalesced pattern that capped rounds 1-4 at ~190 GB/s.
// - Each wave: 2 queries sharing the support reads. Epilogue: h-combine via
//   shfl_xor(32), then 32-lane shuffle softmax (verified k_final pattern),
//   group h handles query h. No workspace, no atomics, deterministic.

#define QN 8192
#define SN 30
#define DN 512
#define QPB 16           // queries per block (8 waves x 2)
#define BLK 512
#define RS 516           // padded support row stride in floats

__global__ __launch_bounds__(BLK, 2)
void resus_one(const float* __restrict__ query,      // [Q][D]
               const float* __restrict__ support,    // [S][D]
               const float* __restrict__ support_y,  // [S]
               const float* __restrict__ support_pr, // [S]
               const float* __restrict__ query_pr,   // [Q]
               const float* __restrict__ fc1_w,      // [D]
               const float* __restrict__ adj_scale,  // [30]
               const float* __restrict__ adj_bias,   // [30]
               const int*   __restrict__ num_samples,// [1]
               float* __restrict__ out)              // [2*Q]
{
    __shared__ float s_lds[SN * RS];   // 61,920 B

    const int tid = threadIdx.x;

    // ---- stage support: coalesced float4 global -> padded LDS rows ----
    {
        const float4* sg = reinterpret_cast<const float4*>(support);
        for (int i = tid; i < SN * (DN / 4); i += BLK) {
            const int row = i >> 7;        // 128 float4 per row
            const int c4  = i & 127;
            *reinterpret_cast<float4*>(s_lds + row * RS + 4 * c4) = sg[i];
        }
    }
    __syncthreads();

    const int lane = tid & 63;
    const int wv   = tid >> 6;            // wave 0..7
    const int h    = lane >> 5;           // d-half 0/1
    const int s    = lane & 31;           // support row (valid < 30)
    const int srow_i = (s < SN) ? s : (SN - 1);

    const int q0 = blockIdx.x * QPB + wv * 2;
    const int q1 = q0 + 1;

    const float* srow = s_lds + srow_i * RS + h * 256;
    const float* qr0  = query + (size_t)q0 * DN + h * 256;  // 2-distinct/wave
    const float* qr1  = query + (size_t)q1 * DN + h * 256;
    const float* wr   = fc1_w + h * 256;

    float sc0 = 0.f, sq0 = 0.f, sc1 = 0.f, sq1 = 0.f;

#define ACC4(QV, SV, WV, SC, SQ) { \
    float d0_ = (QV).x - (SV).x; SC = fmaf((WV).x, fabsf(d0_), SC); SQ = fmaf(d0_, d0_, SQ); \
    float d1_ = (QV).y - (SV).y; SC = fmaf((WV).y, fabsf(d1_), SC); SQ = fmaf(d1_, d1_, SQ); \
    float d2_ = (QV).z - (SV).z; SC = fmaf((WV).z, fabsf(d2_), SC); SQ = fmaf(d2_, d2_, SQ); \
    float d3_ = (QV).w - (SV).w; SC = fmaf((WV).w, fabsf(d3_), SC); SQ = fmaf(d3_, d3_, SQ); }

#pragma unroll 4
    for (int j = 0; j < 32; ++j) {        // 8 d-elements per step
        const float4 sa = *reinterpret_cast<const float4*>(srow + 8 * j);
        const float4 sb = *reinterpret_cast<const float4*>(srow + 8 * j + 4);
        const float4 wa = *reinterpret_cast<const float4*>(wr + 8 * j);
        const float4 wb = *reinterpret_cast<const float4*>(wr + 8 * j + 4);
        const float4 a0 = *reinterpret_cast<const float4*>(qr0 + 8 * j);
        const float4 b0 = *reinterpret_cast<const float4*>(qr0 + 8 * j + 4);
        const float4 a1 = *reinterpret_cast<const float4*>(qr1 + 8 * j);
        const float4 b1 = *reinterpret_cast<const float4*>(qr1 + 8 * j + 4);
        ACC4(a0, sa, wa, sc0, sq0)
        ACC4(b0, sb, wb, sc0, sq0)
        ACC4(a1, sa, wa, sc1, sq1)
        ACC4(b1, sb, wb, sc1, sq1)
    }
#undef ACC4

    // ---- combine d-halves: lane ^ 32 holds the other half, same s ----
    sc0 += __shfl_xor(sc0, 32);
    sq0 += __shfl_xor(sq0, 32);
    sc1 += __shfl_xor(sc1, 32);
    sq1 += __shfl_xor(sq1, 32);

    // ---- group h=0 finishes q0, group h=1 finishes q1 ----
    const bool valid = (s < SN);
    float scv = h ? sc1 : sc0;
    float ssv = h ? sq1 : sq0;
    const int q = h ? q1 : q0;

    float dy = 0.f;
    if (valid)
        dy = support_y[s] - 1.0f / (1.0f + expf(-support_pr[s]));
    if (!valid) { scv = -1e30f; ssv = 0.f; }

    float m = scv;
#pragma unroll
    for (int off = 16; off >= 1; off >>= 1)
        m = fmaxf(m, __shfl_xor(m, off));

    float e   = valid ? expf(scv - m) : 0.f;
    float den = e;
    float num = dy * e;
    float l2  = valid ? sqrtf(ssv) : 0.f;
#pragma unroll
    for (int off = 16; off >= 1; off >>= 1) {
        den += __shfl_xor(den, off);
        num += __shfl_xor(num, off);
        l2  += __shfl_xor(l2, off);
    }

    if (s == 0) {
        const int ns = num_samples[0];
        const float scale = fabsf(adj_scale[ns - 1]);
        const float bias  = adj_bias[ns - 1];
        out[q]      = num / den * scale + bias + query_pr[q];
        out[QN + q] = l2 * (1.0f / (float)SN);
    }
}

extern "C" void kernel_launch(void* const* d_in, const int* in_sizes, int n_in,
                              void* d_out, int out_size, void* d_ws, size_t ws_size,
                              hipStream_t stream)
{
    const float* query      = (const float*)d_in[0];
    const float* support    = (const float*)d_in[1];
    const float* support_y  = (const float*)d_in[2];
    const float* support_pr = (const float*)d_in[3];
    const float* query_pr   = (const float*)d_in[4];
    const float* fc1_w      = (const float*)d_in[5];
    // d_in[6] = fc1_b: cancels in softmax, unused
    const float* adj_scale  = (const float*)d_in[7];
    const float* adj_bias   = (const float*)d_in[8];
    const int*   num_s      = (const int*)d_in[9];
    float* out = (float*)d_out;

    dim3 grid(QN / QPB);     // 512 blocks (2 per CU, LDS-limited)
    hipLaunchKernelGGL(resus_one, grid, dim3(BLK), 0, stream,
                       query, support, support_y, support_pr, query_pr,
                       fc1_w, adj_scale, adj_bias, num_s, out);
}

// Round 6
// 104.463 us; speedup vs baseline: 1.6491x; 1.0074x over previous
//
#include <hip/hip_runtime.h>
#include <math.h>

// RESUS_NN_2327872274812: Q=8192, S=30, D=512.
// lane = (h, s): h = d-half, s = support row. 4 queries per wave.
// - support in LDS, row stride 515 floats (odd): bank = 3s mod 32, injective
//   over s -> per-instr ds_read_b32 is 2-way (h) aliased = free (m136).
//   (Round 5's stride-516 b128 reads were ~8-way quad-conflicted.)
// - query / fc1_w: global loads with 2 distinct addrs per wave (h-groups),
//   distance-1 prefetch into named float4s covers HBM latency at 2 waves/SIMD.
// - 4 q/wave halves LDS+global traffic per element vs round 5.
// - Epilogue: shfl_xor(32) h-combine, then each 32-lane group runs the
//   verified shuffle softmax for its 2 queries. No workspace, no atomics.

#define QN 8192
#define SN 30
#define DN 512
#define BLK 512
#define WPB 8
#define QPW 4            // queries per wave
#define QPB (WPB * QPW)  // 32 queries per block
#define RS 515           // LDS row stride in floats (odd -> conflict-free reads)

__global__ __launch_bounds__(BLK, 2)
void resus_one(const float* __restrict__ query,      // [Q][D]
               const float* __restrict__ support,    // [S][D]
               const float* __restrict__ support_y,  // [S]
               const float* __restrict__ support_pr, // [S]
               const float* __restrict__ query_pr,   // [Q]
               const float* __restrict__ fc1_w,      // [D]
               const float* __restrict__ adj_scale,  // [30]
               const float* __restrict__ adj_bias,   // [30]
               const int*   __restrict__ num_samples,// [1]
               float* __restrict__ out)              // [2*Q]
{
    __shared__ float s_lds[SN * RS];   // 61,800 B

    const int tid  = threadIdx.x;
    const int lane = tid & 63;
    const int wv   = tid >> 6;          // 0..7
    const int h    = lane >> 5;         // d-half 0/1
    const int s    = lane & 31;         // support row (valid < 30)
    const int srow_i = (s < SN) ? s : (SN - 1);   // clamped dup = broadcast

    const int qbase = blockIdx.x * QPB + wv * QPW;

    const float* qr0 = query + (size_t)(qbase + 0) * DN + h * 256;
    const float* qr1 = query + (size_t)(qbase + 1) * DN + h * 256;
    const float* qr2 = query + (size_t)(qbase + 2) * DN + h * 256;
    const float* qr3 = query + (size_t)(qbase + 3) * DN + h * 256;
    const float* wr  = fc1_w + h * 256;
    const float* srow = s_lds + srow_i * RS + h * 256;

    // ---- prologue prefetch (j = 0) before the barrier ----
    float4 c0a = *reinterpret_cast<const float4*>(qr0);
    float4 c0b = *reinterpret_cast<const float4*>(qr0 + 4);
    float4 c1a = *reinterpret_cast<const float4*>(qr1);
    float4 c1b = *reinterpret_cast<const float4*>(qr1 + 4);
    float4 c2a = *reinterpret_cast<const float4*>(qr2);
    float4 c2b = *reinterpret_cast<const float4*>(qr2 + 4);
    float4 c3a = *reinterpret_cast<const float4*>(qr3);
    float4 c3b = *reinterpret_cast<const float4*>(qr3 + 4);
    float4 cwa = *reinterpret_cast<const float4*>(wr);
    float4 cwb = *reinterpret_cast<const float4*>(wr + 4);

    // ---- stage support: coalesced float4 reads -> b32 scatter (one-time) ----
    {
        const float4* sg = reinterpret_cast<const float4*>(support);
        for (int i = tid; i < SN * (DN / 4); i += BLK) {
            const float4 v = sg[i];
            float* d = s_lds + (i >> 7) * RS + 4 * (i & 127);
            d[0] = v.x; d[1] = v.y; d[2] = v.z; d[3] = v.w;
        }
    }
    __syncthreads();

    float sc0 = 0.f, sq0 = 0.f, sc1 = 0.f, sq1 = 0.f;
    float sc2 = 0.f, sq2 = 0.f, sc3 = 0.f, sq3 = 0.f;

#define ACC8(CA, CB, SC, SQ) { float d_; \
    d_ = (CA).x - s0; SC = fmaf(cwa.x, fabsf(d_), SC); SQ = fmaf(d_, d_, SQ); \
    d_ = (CA).y - s1; SC = fmaf(cwa.y, fabsf(d_), SC); SQ = fmaf(d_, d_, SQ); \
    d_ = (CA).z - s2; SC = fmaf(cwa.z, fabsf(d_), SC); SQ = fmaf(d_, d_, SQ); \
    d_ = (CA).w - s3; SC = fmaf(cwa.w, fabsf(d_), SC); SQ = fmaf(d_, d_, SQ); \
    d_ = (CB).x - s4; SC = fmaf(cwb.x, fabsf(d_), SC); SQ = fmaf(d_, d_, SQ); \
    d_ = (CB).y - s5; SC = fmaf(cwb.y, fabsf(d_), SC); SQ = fmaf(d_, d_, SQ); \
    d_ = (CB).z - s6; SC = fmaf(cwb.z, fabsf(d_), SC); SQ = fmaf(d_, d_, SQ); \
    d_ = (CB).w - s7; SC = fmaf(cwb.w, fabsf(d_), SC); SQ = fmaf(d_, d_, SQ); }

#pragma unroll 4
    for (int j = 0; j < 32; ++j) {
        // distance-1 prefetch; jn wraps to 0 at j=31 (in-bounds, discarded)
        const int jn = (j + 1) & 31;
        float4 n0a = *reinterpret_cast<const float4*>(qr0 + 8 * jn);
        float4 n0b = *reinterpret_cast<const float4*>(qr0 + 8 * jn + 4);
        float4 n1a = *reinterpret_cast<const float4*>(qr1 + 8 * jn);
        float4 n1b = *reinterpret_cast<const float4*>(qr1 + 8 * jn + 4);
        float4 n2a = *reinterpret_cast<const float4*>(qr2 + 8 * jn);
        float4 n2b = *reinterpret_cast<const float4*>(qr2 + 8 * jn + 4);
        float4 n3a = *reinterpret_cast<const float4*>(qr3 + 8 * jn);
        float4 n3b = *reinterpret_cast<const float4*>(qr3 + 8 * jn + 4);
        float4 nwa = *reinterpret_cast<const float4*>(wr + 8 * jn);
        float4 nwb = *reinterpret_cast<const float4*>(wr + 8 * jn + 4);

        // support: 8 b32 reads, bank 3s mod 32, 2-way (h) = conflict-free
        const float* sp = srow + 8 * j;
        const float s0 = sp[0], s1 = sp[1], s2 = sp[2], s3 = sp[3];
        const float s4 = sp[4], s5 = sp[5], s6 = sp[6], s7 = sp[7];

        ACC8(c0a, c0b, sc0, sq0)
        ACC8(c1a, c1b, sc1, sq1)
        ACC8(c2a, c2b, sc2, sq2)
        ACC8(c3a, c3b, sc3, sq3)

        c0a = n0a; c0b = n0b; c1a = n1a; c1b = n1b;
        c2a = n2a; c2b = n2b; c3a = n3a; c3b = n3b;
        cwa = nwa; cwb = nwb;
    }
#undef ACC8

    // ---- combine d-halves (lane ^ 32 = same s, other half) ----
    sc0 += __shfl_xor(sc0, 32); sq0 += __shfl_xor(sq0, 32);
    sc1 += __shfl_xor(sc1, 32); sq1 += __shfl_xor(sq1, 32);
    sc2 += __shfl_xor(sc2, 32); sq2 += __shfl_xor(sq2, 32);
    sc3 += __shfl_xor(sc3, 32); sq3 += __shfl_xor(sq3, 32);

    // ---- group h finishes queries (qbase + 2h) and (qbase + 2h + 1) ----
    const bool valid = (s < SN);
    float dy = 0.f;
    if (valid)
        dy = support_y[s] - 1.0f / (1.0f + expf(-support_pr[s]));

    const int ns = num_samples[0];
    const float ascale = fabsf(adj_scale[ns - 1]);
    const float abias  = adj_bias[ns - 1];

    float scA = h ? sc2 : sc0;  float sqA = h ? sq2 : sq0;
    float scB = h ? sc3 : sc1;  float sqB = h ? sq3 : sq1;
    const int qA = qbase + 2 * h;
    const int qB = qA + 1;

#define FINISH(SCV, SQV, QI) { \
    float scv = (SCV), ssv = (SQV); \
    if (!valid) { scv = -1e30f; ssv = 0.f; } \
    float m_ = scv; \
    _Pragma("unroll") \
    for (int off = 16; off >= 1; off >>= 1) m_ = fmaxf(m_, __shfl_xor(m_, off)); \
    float e_   = valid ? expf(scv - m_) : 0.f; \
    float den_ = e_; \
    float num_ = dy * e_; \
    float l2_  = valid ? sqrtf(ssv) : 0.f; \
    _Pragma("unroll") \
    for (int off = 16; off >= 1; off >>= 1) { \
        den_ += __shfl_xor(den_, off); \
        num_ += __shfl_xor(num_, off); \
        l2_  += __shfl_xor(l2_,  off); \
    } \
    if (s == 0) { \
        out[(QI)]      = num_ / den_ * ascale + abias + query_pr[(QI)]; \
        out[QN + (QI)] = l2_ * (1.0f / (float)SN); \
    } }

    FINISH(scA, sqA, qA)
    FINISH(scB, sqB, qB)
#undef FINISH
}

extern "C" void kernel_launch(void* const* d_in, const int* in_sizes, int n_in,
                              void* d_out, int out_size, void* d_ws, size_t ws_size,
                              hipStream_t stream)
{
    const float* query      = (const float*)d_in[0];
    const float* support    = (const float*)d_in[1];
    const float* support_y  = (const float*)d_in[2];
    const float* support_pr = (const float*)d_in[3];
    const float* query_pr   = (const float*)d_in[4];
    const float* fc1_w      = (const float*)d_in[5];
    // d_in[6] = fc1_b: cancels in softmax, unused
    const float* adj_scale  = (const float*)d_in[7];
    const float* adj_bias   = (const float*)d_in[8];
    const int*   num_s      = (const int*)d_in[9];
    float* out = (float*)d_out;

    dim3 grid(QN / QPB);     // 256 blocks, 1 per CU
    hipLaunchKernelGGL(resus_one, grid, dim3(BLK), 0, stream,
                       query, support, support_y, support_pr, query_pr,
                       fc1_w, adj_scale, adj_bias, num_s, out);
}